// Round 2
// baseline (3112.920 us; speedup 1.0000x reference)
//
#include <hip/hip_runtime.h>

#define LBL 64
#define TT 1024
#define BB 256
#define BOS 62
#define EOS 63
#define NEGV -10000.0f

__device__ __forceinline__ float bcast_lane(float v, int l) {
    return __uint_as_float(__builtin_amdgcn_readlane(__float_as_uint(v), l));
}

// One WAVE per sentence: 64 threads, lane = next-label n.
// fv broadcast via v_readlane (no LDS, no barriers in the step loop).
// Argmax = tournament tree, strict '>' right-wins => first-occurrence (np.argmax).
__global__ __launch_bounds__(64, 1) void viterbi_kernel(
    const float* __restrict__ X, const float* __restrict__ trans,
    float* __restrict__ out)
{
    __shared__ unsigned char bp[TT][LBL];   // 64 KiB backpointers
    __shared__ unsigned char path_s[TT];

    const int lane = threadIdx.x;           // next-label n
    const int b    = blockIdx.x;

    // transition column for this n: tc[p] = trans[p][n]  (registers, loaded once)
    float tc[LBL];
#pragma unroll
    for (int p = 0; p < LBL; ++p) tc[p] = trans[p * LBL + lane];

    const float* Xb = X + (size_t)b * TT * LBL;

    // emission prefetch ring (4 deep covers HBM latency at ~700cyc/step)
    float e0 = Xb[0 * LBL + lane];
    float e1 = Xb[1 * LBL + lane];
    float e2 = Xb[2 * LBL + lane];
    float e3 = Xb[3 * LBL + lane];

    float fvv = (lane == BOS) ? 0.0f : NEGV;

    for (int t = 0; t < TT; ++t) {
        // s[p] = fv[p] + trans[p][n] — 64 independent readlane+add
        float s[LBL];
#pragma unroll
        for (int p = 0; p < LBL; ++p)
            s[p] = bcast_lane(fvv, p) + tc[p];

        // tournament argmax, depth 6, first-occurrence tie-break
        float v32[32]; int i32[32];
#pragma unroll
        for (int k = 0; k < 32; ++k) {
            bool g = s[2*k+1] > s[2*k];
            v32[k] = g ? s[2*k+1] : s[2*k];
            i32[k] = g ? (2*k+1)  : (2*k);
        }
        float v16[16]; int i16[16];
#pragma unroll
        for (int k = 0; k < 16; ++k) {
            bool g = v32[2*k+1] > v32[2*k];
            v16[k] = g ? v32[2*k+1] : v32[2*k];
            i16[k] = g ? i32[2*k+1] : i32[2*k];
        }
        float v8[8]; int i8_[8];
#pragma unroll
        for (int k = 0; k < 8; ++k) {
            bool g = v16[2*k+1] > v16[2*k];
            v8[k]  = g ? v16[2*k+1] : v16[2*k];
            i8_[k] = g ? i16[2*k+1] : i16[2*k];
        }
        float v4[4]; int i4_[4];
#pragma unroll
        for (int k = 0; k < 4; ++k) {
            bool g = v8[2*k+1] > v8[2*k];
            v4[k]  = g ? v8[2*k+1] : v8[2*k];
            i4_[k] = g ? i8_[2*k+1] : i8_[2*k];
        }
        float v2[2]; int i2_[2];
#pragma unroll
        for (int k = 0; k < 2; ++k) {
            bool g = v4[2*k+1] > v4[2*k];
            v2[k]  = g ? v4[2*k+1] : v4[2*k];
            i2_[k] = g ? i4_[2*k+1] : i4_[2*k];
        }
        bool g = v2[1] > v2[0];
        float m = g ? v2[1] : v2[0];
        int  mi = g ? i2_[1] : i2_[0];

        bp[t][lane] = (unsigned char)mi;     // fire-and-forget

        float e = e0; e0 = e1; e1 = e2; e2 = e3;
        int tp = (t + 4 < TT) ? (t + 4) : (TT - 1);   // branchless guard
        e3 = Xb[(size_t)tp * LBL + lane];
        fvv = m + e;                          // exact f32 add, matches numpy
    }

    // termination: term[n] = fv[n] + trans[n][EOS]; wave-wide argmax via readlane
    float term = fvv + trans[lane * LBL + EOS];
    float ts[LBL];
#pragma unroll
    for (int p = 0; p < LBL; ++p) ts[p] = bcast_lane(term, p);
    float w32[32]; int j32[32];
#pragma unroll
    for (int k = 0; k < 32; ++k) {
        bool gg = ts[2*k+1] > ts[2*k];
        w32[k] = gg ? ts[2*k+1] : ts[2*k];
        j32[k] = gg ? (2*k+1)   : (2*k);
    }
    float w16[16]; int j16[16];
#pragma unroll
    for (int k = 0; k < 16; ++k) {
        bool gg = w32[2*k+1] > w32[2*k];
        w16[k] = gg ? w32[2*k+1] : w32[2*k];
        j16[k] = gg ? j32[2*k+1] : j32[2*k];
    }
    float w8[8]; int j8[8];
#pragma unroll
    for (int k = 0; k < 8; ++k) {
        bool gg = w16[2*k+1] > w16[2*k];
        w8[k] = gg ? w16[2*k+1] : w16[2*k];
        j8[k] = gg ? j16[2*k+1] : j16[2*k];
    }
    float w4[4]; int j4[4];
#pragma unroll
    for (int k = 0; k < 4; ++k) {
        bool gg = w8[2*k+1] > w8[2*k];
        w4[k] = gg ? w8[2*k+1] : w8[2*k];
        j4[k] = gg ? j8[2*k+1] : j8[2*k];
    }
    float w2[2]; int j2[2];
#pragma unroll
    for (int k = 0; k < 2; ++k) {
        bool gg = w4[2*k+1] > w4[2*k];
        w2[k] = gg ? w4[2*k+1] : w4[2*k];
        j2[k] = gg ? j4[2*k+1] : j4[2*k];
    }
    bool gg = w2[1] > w2[0];
    float bestv = gg ? w2[1] : w2[0];
    int   bl    = gg ? j2[1] : j2[0];

    if (lane == 0) out[b] = bestv;
    __syncthreads();   // bp visible (single wave: cheap; also orders LDS)

    // sequential backtrack in LDS (lane 0): 1024 dependent ds_read_u8
    if (lane == 0) {
        int tag = bl;
        for (int t = TT - 1; t >= 0; --t) {
            path_s[t] = (unsigned char)tag;
            tag = bp[t][tag];
        }
    }
    __syncthreads();

    // coalesced float path write
    float* po = out + BB + (size_t)b * TT;
#pragma unroll
    for (int i = 0; i < TT / LBL; ++i)
        po[i * LBL + lane] = (float)path_s[i * LBL + lane];
}

extern "C" void kernel_launch(void* const* d_in, const int* in_sizes, int n_in,
                              void* d_out, int out_size, void* d_ws, size_t ws_size,
                              hipStream_t stream)
{
    const float* X     = (const float*)d_in[0];   // [256, 1024, 64]
    const float* trans = (const float*)d_in[1];   // [64, 64]
    float* out = (float*)d_out;                   // [256] scores ++ [256*1024] path

    viterbi_kernel<<<dim3(BB), dim3(64), 0, stream>>>(X, trans, out);
}

// Round 3
// 778.793 us; speedup vs baseline: 3.9971x; 3.9971x over previous
//
#include <hip/hip_runtime.h>

#define LBL 64
#define TT 1024
#define BB 256
#define BOS 62
#define EOS 63
#define NEGV -10000.0f
#define SPB 2   // sentences per block

__device__ __forceinline__ float bcast_lane(float v, int l) {
    return __uint_as_float(__builtin_amdgcn_readlane(__float_as_uint(v), l));
}

// 2 sentences per block, 8 waves (512 threads): waves 0-3 = sentence A,
// waves 4-7 = sentence B. Within a sentence, wave ws owns prev-labels
// [16*ws, 16*ws+16); lane = next-label n. One barrier per step; partials
// exchanged via conflict-free b32 LDS arrays; idx lookup off critical path.
__global__ __launch_bounds__(512, 1) void viterbi_kernel(
    const float* __restrict__ X, const float* __restrict__ trans,
    float* __restrict__ out)
{
    __shared__ unsigned char bp[SPB][TT][LBL];      // 128 KiB backpointers
    __shared__ float pval[SPB][2][4][LBL];          // 4 KiB partial maxima
    __shared__ int   pidx[SPB][2][4][LBL];          // 4 KiB partial arg (0..15)
    __shared__ float termv[SPB][LBL];
    __shared__ unsigned char path_s[SPB][TT];

    const int tid  = threadIdx.x;
    const int lane = tid & 63;              // next-label n
    const int s    = tid >> 8;              // sentence half 0/1
    const int ws   = (tid >> 6) & 3;        // wave index within sentence
    const int b    = blockIdx.x * SPB + s;  // sentence id

    // wave-uniform (SGPR) base of this wave's prev-label range
    const int wbase = ((__builtin_amdgcn_readfirstlane(tid) >> 6) & 3) << 4;

    // transition columns for this wave's 16 prev labels (registers)
    float tc[16];
#pragma unroll
    for (int i = 0; i < 16; ++i)
        tc[i] = trans[(wbase + i) * LBL + lane];

    const float* Xb = X + (size_t)b * TT * LBL;

    // emission prefetch ring
    float e0 = Xb[0 * LBL + lane];
    float e1 = Xb[1 * LBL + lane];
    float e2 = Xb[2 * LBL + lane];
    float e3 = Xb[3 * LBL + lane];

    float fvv = (lane == BOS) ? 0.0f : NEGV;

    for (int t = 0; t < TT; ++t) {
        // ---- partial over p in [wbase, wbase+16), first-occurrence tie-break ----
        float sc[16];
#pragma unroll
        for (int i = 0; i < 16; ++i)
            sc[i] = bcast_lane(fvv, wbase + i) + tc[i];

        float v8[8]; int i8_[8];
#pragma unroll
        for (int k = 0; k < 8; ++k) {
            bool g = sc[2*k+1] > sc[2*k];
            v8[k]  = g ? sc[2*k+1] : sc[2*k];
            i8_[k] = g ? (2*k+1)   : (2*k);
        }
        float v4[4]; int i4_[4];
#pragma unroll
        for (int k = 0; k < 4; ++k) {
            bool g = v8[2*k+1] > v8[2*k];
            v4[k]  = g ? v8[2*k+1] : v8[2*k];
            i4_[k] = g ? i8_[2*k+1] : i8_[2*k];
        }
        float v2[2]; int i2_[2];
#pragma unroll
        for (int k = 0; k < 2; ++k) {
            bool g = v4[2*k+1] > v4[2*k];
            v2[k]  = g ? v4[2*k+1] : v4[2*k];
            i2_[k] = g ? i4_[2*k+1] : i4_[2*k];
        }
        {
            bool g = v2[1] > v2[0];
            pval[s][t & 1][ws][lane] = g ? v2[1]  : v2[0];
            pidx[s][t & 1][ws][lane] = g ? i2_[1] : i2_[0];
        }
        __syncthreads();

        // ---- combine 4 wave partials (replicated; ascending w = first-occurrence) ----
        float c0 = pval[s][t & 1][0][lane];
        float c1 = pval[s][t & 1][1][lane];
        float c2 = pval[s][t & 1][2][lane];
        float c3 = pval[s][t & 1][3][lane];
        bool g1 = c1 > c0;  float m01 = g1 ? c1 : c0;
        bool g3 = c3 > c2;  float m23 = g3 ? c3 : c2;
        bool gg = m23 > m01;
        float m = gg ? m23 : m01;                 // fv critical path: 3 max ops

        if (ws == 0) {                            // backpointer: off critical path
            int w01 = g1 ? 1 : 0;
            int w23 = g3 ? 3 : 2;
            int winw = gg ? w23 : w01;
            int li = pidx[s][t & 1][winw][lane];
            bp[s][t][lane] = (unsigned char)((winw << 4) + li);
        }

        float e = e0; e0 = e1; e1 = e2; e2 = e3;
        int tp = (t + 4 < TT) ? (t + 4) : (TT - 1);   // branchless guard
        e3 = Xb[(size_t)tp * LBL + lane];
        fvv = m + e;   // exact f32 add — bitwise-identical to numpy
        // no 2nd barrier: slot t&1 next written at t+2, after barrier t+1,
        // which all waves reach only after completing step-t reads.
    }

    // ---- termination: term[n] = fv[n] + trans[n][EOS] ----
    if (ws == 0) termv[s][lane] = fvv + trans[lane * LBL + EOS];
    __syncthreads();

    // ---- argmax + sequential backtrack (one thread per sentence, concurrent) ----
    if ((tid & 255) == 0) {
        float bestv = termv[s][0]; int bl = 0;
        for (int n = 1; n < LBL; ++n)
            if (termv[s][n] > bestv) { bestv = termv[s][n]; bl = n; }
        out[b] = bestv;
        int tag = bl;
        for (int t = TT - 1; t >= 0; --t) {
            path_s[s][t] = (unsigned char)tag;
            tag = bp[s][t][tag];
        }
    }
    __syncthreads();

    // coalesced float path write (256 threads per sentence)
    float* po = out + BB + (size_t)b * TT;
    const int lt = tid & 255;
#pragma unroll
    for (int i = 0; i < TT / 256; ++i)
        po[i * 256 + lt] = (float)path_s[s][i * 256 + lt];
}

extern "C" void kernel_launch(void* const* d_in, const int* in_sizes, int n_in,
                              void* d_out, int out_size, void* d_ws, size_t ws_size,
                              hipStream_t stream)
{
    const float* X     = (const float*)d_in[0];   // [256, 1024, 64]
    const float* trans = (const float*)d_in[1];   // [64, 64]
    float* out = (float*)d_out;                   // [256] scores ++ [256*1024] path

    viterbi_kernel<<<dim3(BB / SPB), dim3(512), 0, stream>>>(X, trans, out);
}

// Round 4
// 575.337 us; speedup vs baseline: 5.4106x; 1.3536x over previous
//
#include <hip/hip_runtime.h>

#define LBL 64
#define TT 1024
#define BB 256
#define BOS 62
#define EOS 63
#define NEGV -10000.0f
#define SPB 2   // sentences per block

__device__ __forceinline__ float bcast_lane(float v, int l) {
    return __uint_as_float(__builtin_amdgcn_readlane(__float_as_uint(v), l));
}

// 2 sentences per block, 8 waves (512 threads). Within a sentence, wave ws
// owns prev-labels [16*ws, 16*ws+16); lane = next-label n. One barrier/step.
// KEY CHANGE vs r3: emissions are loaded in 8-step register banks, issued
// right after a barrier, so the per-step __syncthreads vmcnt(0) drain no
// longer serializes against a fresh HBM/L3 load every step.
__global__ __launch_bounds__(512, 1) void viterbi_kernel(
    const float* __restrict__ X, const float* __restrict__ trans,
    float* __restrict__ out)
{
    __shared__ unsigned char bp[SPB][TT][LBL];      // 128 KiB backpointers
    __shared__ float pval[SPB][2][4][LBL];          // partial maxima
    __shared__ int   pidx[SPB][2][4][LBL];          // partial arg (0..15)
    __shared__ float termv[SPB][LBL];
    __shared__ unsigned char path_s[SPB][TT];

    const int tid  = threadIdx.x;
    const int lane = tid & 63;              // next-label n
    const int s    = tid >> 8;              // sentence half 0/1
    const int ws   = (tid >> 6) & 3;        // wave index within sentence
    const int b    = blockIdx.x * SPB + s;  // sentence id

    const int wbase = ((__builtin_amdgcn_readfirstlane(tid) >> 6) & 3) << 4;

    float tc[16];
#pragma unroll
    for (int i = 0; i < 16; ++i)
        tc[i] = trans[(wbase + i) * LBL + lane];

    const float* Xb = X + (size_t)b * TT * LBL;

    float fvv = (lane == BOS) ? 0.0f : NEGV;

    // one Viterbi step; par = t&1 (compile-time const at each unrolled site)
    auto STEP = [&](int t, int par, float e) {
        float sc[16];
#pragma unroll
        for (int i = 0; i < 16; ++i)
            sc[i] = bcast_lane(fvv, wbase + i) + tc[i];

        float v8[8]; int i8_[8];
#pragma unroll
        for (int k = 0; k < 8; ++k) {
            bool g = sc[2*k+1] > sc[2*k];
            v8[k]  = g ? sc[2*k+1] : sc[2*k];
            i8_[k] = g ? (2*k+1)   : (2*k);
        }
        float v4[4]; int i4_[4];
#pragma unroll
        for (int k = 0; k < 4; ++k) {
            bool g = v8[2*k+1] > v8[2*k];
            v4[k]  = g ? v8[2*k+1] : v8[2*k];
            i4_[k] = g ? i8_[2*k+1] : i8_[2*k];
        }
        float v2[2]; int i2_[2];
#pragma unroll
        for (int k = 0; k < 2; ++k) {
            bool g = v4[2*k+1] > v4[2*k];
            v2[k]  = g ? v4[2*k+1] : v4[2*k];
            i2_[k] = g ? i4_[2*k+1] : i4_[2*k];
        }
        {
            bool g = v2[1] > v2[0];
            pval[s][par][ws][lane] = g ? v2[1]  : v2[0];
            pidx[s][par][ws][lane] = g ? i2_[1] : i2_[0];
        }
        __syncthreads();

        float c0 = pval[s][par][0][lane];
        float c1 = pval[s][par][1][lane];
        float c2 = pval[s][par][2][lane];
        float c3 = pval[s][par][3][lane];
        bool g1 = c1 > c0;  float m01 = g1 ? c1 : c0;
        bool g3 = c3 > c2;  float m23 = g3 ? c3 : c2;
        bool gg = m23 > m01;
        float m = gg ? m23 : m01;                 // fv critical path: 3 maxes

        if (ws == 0) {                            // backpointer off critical path
            int w01 = g1 ? 1 : 0;
            int w23 = g3 ? 3 : 2;
            int winw = gg ? w23 : w01;
            int li = pidx[s][par][winw][lane];
            bp[s][t][lane] = (unsigned char)((winw << 4) + li);
        }
        fvv = m + e;   // exact f32 add — bitwise-identical to numpy
    };

    // emission bank prefetch: 8 steps per bank, double-buffered registers
    float eA[8], eB[8];
#pragma unroll
    for (int j = 0; j < 8; ++j) eA[j] = Xb[j * LBL + lane];

    for (int g = 0; g < TT / 8; g += 2) {
        const int tA = g * 8, tB = (g + 1) * 8;

        STEP(tA + 0, 0, eA[0]);
        // issue next bank's loads just after a barrier: next drain is ~1 step away
        {
#pragma unroll
            for (int j = 0; j < 8; ++j) {
                int st = tB + j; if (st > TT - 1) st = TT - 1;
                eB[j] = Xb[(size_t)st * LBL + lane];
            }
        }
        STEP(tA + 1, 1, eA[1]);
        STEP(tA + 2, 0, eA[2]);
        STEP(tA + 3, 1, eA[3]);
        STEP(tA + 4, 0, eA[4]);
        STEP(tA + 5, 1, eA[5]);
        STEP(tA + 6, 0, eA[6]);
        STEP(tA + 7, 1, eA[7]);

        STEP(tB + 0, 0, eB[0]);
        {
#pragma unroll
            for (int j = 0; j < 8; ++j) {
                int st = tB + 8 + j; if (st > TT - 1) st = TT - 1;
                eA[j] = Xb[(size_t)st * LBL + lane];
            }
        }
        STEP(tB + 1, 1, eB[1]);
        STEP(tB + 2, 0, eB[2]);
        STEP(tB + 3, 1, eB[3]);
        STEP(tB + 4, 0, eB[4]);
        STEP(tB + 5, 1, eB[5]);
        STEP(tB + 6, 0, eB[6]);
        STEP(tB + 7, 1, eB[7]);
    }

    // ---- termination: term[n] = fv[n] + trans[n][EOS] ----
    if (ws == 0) termv[s][lane] = fvv + trans[lane * LBL + EOS];
    __syncthreads();

    // ---- argmax + sequential backtrack (one thread per sentence) ----
    if ((tid & 255) == 0) {
        float bestv = termv[s][0]; int bl = 0;
        for (int n = 1; n < LBL; ++n)
            if (termv[s][n] > bestv) { bestv = termv[s][n]; bl = n; }
        out[b] = bestv;
        int tag = bl;
        for (int t = TT - 1; t >= 0; --t) {
            path_s[s][t] = (unsigned char)tag;
            tag = bp[s][t][tag];
        }
    }
    __syncthreads();

    // coalesced float path write (256 threads per sentence)
    float* po = out + BB + (size_t)b * TT;
    const int lt = tid & 255;
#pragma unroll
    for (int i = 0; i < TT / 256; ++i)
        po[i * 256 + lt] = (float)path_s[s][i * 256 + lt];
}

extern "C" void kernel_launch(void* const* d_in, const int* in_sizes, int n_in,
                              void* d_out, int out_size, void* d_ws, size_t ws_size,
                              hipStream_t stream)
{
    const float* X     = (const float*)d_in[0];   // [256, 1024, 64]
    const float* trans = (const float*)d_in[1];   // [64, 64]
    float* out = (float*)d_out;                   // [256] scores ++ [256*1024] path

    viterbi_kernel<<<dim3(BB / SPB), dim3(512), 0, stream>>>(X, trans, out);
}